// Round 13
// baseline (766.450 us; speedup 1.0000x reference)
//
#include <hip/hip_runtime.h>
#include <cmath>

constexpr int N_  = 20000;
constexpr int E_  = 320000;
constexpr int NE_ = 4;
constexpr int G_  = 16;
constexpr int CAP = 96;
constexpr int TAB = 4096;
constexpr float RMAXF = 5.0f;
constexpr float PI_F  = 3.14159265358979323846f;
constexpr float S3  = 1.7320508075688772f;
constexpr float S5  = 2.2360679774997896f;
constexpr float S15 = 3.8729833462074170f;
constexpr float KC_ = 0.6324555320336759f; // sqrt(2/RMAX)

typedef unsigned short u16;
typedef unsigned int   u32;
typedef _Float16 f16;
typedef _Float16 f16x2 __attribute__((ext_vector_type(2)));

#define DEV static __device__ __forceinline__

// fallback scratch (440 MB) in case ws_size is too small
__device__ float g_fallback[110000000];

DEV float sigmoidf_(float x){ return 1.0f/(1.0f+__expf(-x)); }

// bf16 <-> fp32 (RTNE pack)
DEV float b2f(u16 u){ return __uint_as_float(((u32)u)<<16); }
DEV u16  f2b(float f){
  u32 x = __float_as_uint(f);
  return (u16)((x + 0x7FFFu + ((x>>16)&1u)) >> 16);
}
// fp16 <-> fp32
DEV u16  f2h(float f){ union{f16 h; u16 u;} v; v.h=(f16)f; return v.u; }
DEV float h2f(u16 u){ union{u16 u2; f16 h;} v; v.u2=u; return (float)v.h; }

DEV f16x2 u2h(u32 x){ union{u32 u; f16x2 h;} v; v.u=x; return v.h; }
DEV u32 h2u(f16x2 h){ union{u32 u; f16x2 h;} v; v.h=h; return v.u; }
DEV u32 pkh(float a, float b){ f16x2 h; h.x=(f16)a; h.y=(f16)b; return h2u(h); }

DEV void ld4(const float* __restrict__ p, float* d){
  float4 a = ((const float4*)p)[0];
  d[0]=a.x; d[1]=a.y; d[2]=a.z; d[3]=a.w;
}
DEV void st8h(u16* p, const float* d){
  uint4 v;
  v.x = pkh(d[0],d[1]); v.y = pkh(d[2],d[3]);
  v.z = pkh(d[4],d[5]); v.w = pkh(d[6],d[7]);
  *(uint4*)p = v;
}
// load f16 Y row (l=1..8) into Yb[8]
DEV void ldY(const u16* __restrict__ p, float* Yb){
  ushort4 a = *(const ushort4*)p;
  ushort4 b = *(const ushort4*)(p+4);
  Yb[0]=h2f(a.x); Yb[1]=h2f(a.y); Yb[2]=h2f(a.z); Yb[3]=h2f(a.w);
  Yb[4]=h2f(b.x); Yb[5]=h2f(b.y); Yb[6]=h2f(b.z); Yb[7]=h2f(b.w);
}

// lerp one table entry (idx in [0,256)) at knot coordinate i0+f
DEV float tlerp(const u16* __restrict__ tab, int i0, float f, int idx){
  return h2f(tab[i0*256+idx])*(1.0f-f) + h2f(tab[(i0+1)*256+idx])*f;
}

// ---------------- edge renumbering: rcv-sorted dense p-space ----------------
__global__ void k_cnt(const int* __restrict__ ei, int* __restrict__ cntR){
  int e = blockIdx.x*256 + threadIdx.x;
  atomicAdd(&cntR[ei[E_+e]], 1);
}

__global__ void k_scan(const int* __restrict__ cntR, int* __restrict__ offR){
  __shared__ int part[256];
  int t = threadIdx.x;
  constexpr int CH = (N_+255)/256;
  int base = t*CH;
  int s=0;
  for (int i=0;i<CH;++i){ int idx=base+i; if(idx<N_) s+=cntR[idx]; }
  part[t]=s; __syncthreads();
  for (int d=1; d<256; d<<=1){
    int v = (t>=d)? part[t-d] : 0;
    __syncthreads();
    part[t]+=v;
    __syncthreads();
  }
  int run = (t==0)?0:part[t-1];
  for (int i=0;i<CH;++i){ int idx=base+i; if(idx<N_){ offR[idx]=run; run+=cntR[idx]; } }
  if (t==255) offR[N_]=run;
}

__global__ void k_perm(const int* __restrict__ ei, const int* __restrict__ offR,
                       int* __restrict__ cntR2, int* __restrict__ cntS,
                       int* __restrict__ pe, int* __restrict__ pSnd, int* __restrict__ pRcv,
                       int* __restrict__ listS){
  int e = blockIdx.x*256 + threadIdx.x;
  int s = ei[e], r = ei[E_+e];
  int p = offR[r] + atomicAdd(&cntR2[r], 1);
  pe[p] = e; pSnd[p] = s; pRcv[p] = r;
  int q = atomicAdd(&cntS[s], 1); if (q < CAP) listS[s*CAP+q] = p;
}

// ---------------- weight precompute: composite matrices + WembUp + CC ----------------
__global__ void k_pre(const float* __restrict__ Wout0, const float* __restrict__ Wup1,
                      const float* __restrict__ Wskip0, const float* __restrict__ wread0,
                      const float* __restrict__ Wemb, const float* __restrict__ Wup0,
                      const float* __restrict__ Wr1, const float* __restrict__ Wout1,
                      float* __restrict__ WA, float* __restrict__ sa,
                      float* __restrict__ va, float* __restrict__ sv,
                      float* __restrict__ WembUp, float* __restrict__ CC){
  int t = threadIdx.x;
  for (int idx=t; idx<4096; idx+=256){
    int c = idx>>6, d = idx&63;
    float acc=0.f;
    for (int m=0;m<64;++m) acc += Wout0[c*64+m]*Wup1[m*64+d];
    WA[idx]=acc;
  }
  {
    int k = t>>6, d = t&63;
    float acc=0.f;
    for (int m=0;m<64;++m) acc += Wskip0[k*64+m]*Wup1[m*64+d];
    sa[t]=acc;
    float acc2=0.f;
    for (int j=0;j<64;++j) acc2 += Wemb[k*64+j]*Wup0[j*64+d];
    WembUp[t]=acc2;
  }
  // CC[j*64+c] = sum_k Wr1[k*16+j]*Wout1[c*64+k]   (folds dh2+ga1 matmuls)
  for (int idx=t; idx<1024; idx+=256){
    int j = idx>>6, c = idx&63;
    float acc=0.f;
    for (int k=0;k<64;++k) acc += Wr1[k*16+j]*Wout1[c*64+k];
    CC[idx]=acc;
  }
  if (t<64){
    float acc=0.f;
    for (int d=0;d<64;++d) acc += Wout0[t*64+d]*wread0[d];
    va[t]=acc;
  }
  if (t<4){
    float acc=0.f;
    for (int d=0;d<64;++d) acc += Wskip0[t*64+d]*wread0[d];
    sv[t]=acc;
  }
}

// ---------------- radial table build: tab[i][256] = [R0|R1|q0|q1](r_i), f16 ----------------
__global__ __launch_bounds__(256, 2)
void k_rtab(const float* __restrict__ W1g, const float* __restrict__ W2g,
            u16* __restrict__ tab){
  __shared__ float sW1[1024];   // [layer][8][64]
  __shared__ u32   sW2h[4096];  // [layer][32 kp][64 c]
  __shared__ u32   sAh[32*36];
  int t = threadIdx.x;
  for (int i=t;i<1024;i+=256) sW1[i]=W1g[i];
  for (int i=t;i<4096;i+=256){
    int L = i>>11, rem = i&2047, kp = rem>>6, c = rem&63;
    sW2h[i] = pkh(W2g[L*4096 + (2*kp)*64 + c], W2g[L*4096 + (2*kp+1)*64 + c]);
  }
  __syncthreads();
  int wid=t>>6, lane=t&63, q=lane>>3, j=lane&7, c0=j*8;
  int slot = wid*8 + q;
  int knot = blockIdx.x*32 + slot;
  bool valid = (knot <= TAB);
  float rad = fmaxf((float)knot * (RMAXF/(float)TAB), 1e-6f);
  float inv = 1.0f/rad;
  float tt = rad*(1.0f/RMAXF);
  float fc = 0.0f, dfc = 0.0f;
  if (tt < 1.0f){
    float t2=tt*tt, t4=t2*t2, t5=t4*tt, t6=t5*tt, t7=t6*tt, t8=t7*tt;
    fc  = 1.0f - 28.0f*t6 + 48.0f*t7 - 21.0f*t8;
    dfc = (-168.0f*t5 + 336.0f*t6 - 168.0f*t7)*(1.0f/RMAXF);
  }
  float th = rad*(PI_F/RMAXF);
  float s1 = __sinf(th), c1 = __cosf(th);
  float base = KC_*inv*fc;
  float efv[8], gfv[8];
  {
    float sb = s1, cb = c1;
    #pragma unroll
    for (int b=0;b<8;++b){
      efv[b] = base*sb;
      float wb_ = (float)(b+1)*(PI_F/RMAXF);
      float rb  = KC_*sb*inv;
      float drb = KC_*(wb_*cb - sb*inv)*inv;
      gfv[b] = drb*fc + rb*dfc;
      float sn = sb*c1 + cb*s1;
      cb = cb*c1 - sb*s1;
      sb = sn;
    }
  }
  u32* myAh = sAh + slot*36;
  for (int L=0; L<2; ++L){
    const float* w1 = sW1 + L*512;
    const u32*  w2h = sW2h + L*2048;
    float zz[8]={0,0,0,0,0,0,0,0};
    float wgv[8]={0,0,0,0,0,0,0,0};
    #pragma unroll 4
    for (int b=0;b<8;++b){
      float efb = efv[b], gfb = gfv[b];
      const float4* w=(const float4*)(w1 + b*64 + c0);
      float4 wa=w[0], wb=w[1];
      zz[0]+=efb*wa.x; zz[1]+=efb*wa.y; zz[2]+=efb*wa.z; zz[3]+=efb*wa.w;
      zz[4]+=efb*wb.x; zz[5]+=efb*wb.y; zz[6]+=efb*wb.z; zz[7]+=efb*wb.w;
      wgv[0]+=gfb*wa.x; wgv[1]+=gfb*wa.y; wgv[2]+=gfb*wa.z; wgv[3]+=gfb*wa.w;
      wgv[4]+=gfb*wb.x; wgv[5]+=gfb*wb.y; wgv[6]+=gfb*wb.z; wgv[7]+=gfb*wb.w;
    }
    float a[8], dv[8];
    #pragma unroll
    for (int i=0;i<8;++i){
      float sg = sigmoidf_(zz[i]);
      a[i]  = zz[i]*sg;
      float sp = sg*(1.0f + zz[i]*(1.0f - sg));
      dv[i] = wgv[i]*sp;
    }
    // pass 1: R[c] = sum_k a[k]*W2[k][c]
    {
      uint4 av;
      av.x = pkh(a[0],a[1]); av.y = pkh(a[2],a[3]);
      av.z = pkh(a[4],a[5]); av.w = pkh(a[6],a[7]);
      *(uint4*)(myAh + 4*j) = av;
    }
    {
      float r0=0.f,r1=0.f,r2=0.f,r3=0.f,r4=0.f,r5=0.f,r6=0.f,r7=0.f;
      #pragma unroll 2
      for (int kp4=0; kp4<8; ++kp4){
        uint4 dq = *(const uint4*)(myAh + 4*kp4);
        #pragma unroll
        for (int i=0;i<4;++i){
          u32 du = (i==0)?dq.x:(i==1)?dq.y:(i==2)?dq.z:dq.w;
          f16x2 dh = u2h(du);
          const u32* wrow = w2h + (4*kp4+i)*64 + c0;
          uint4 w0 = *(const uint4*)(wrow);
          uint4 w1v = *(const uint4*)(wrow+4);
          r0 = __builtin_amdgcn_fdot2(dh, u2h(w0.x),  r0, false);
          r1 = __builtin_amdgcn_fdot2(dh, u2h(w0.y),  r1, false);
          r2 = __builtin_amdgcn_fdot2(dh, u2h(w0.z),  r2, false);
          r3 = __builtin_amdgcn_fdot2(dh, u2h(w0.w),  r3, false);
          r4 = __builtin_amdgcn_fdot2(dh, u2h(w1v.x), r4, false);
          r5 = __builtin_amdgcn_fdot2(dh, u2h(w1v.y), r5, false);
          r6 = __builtin_amdgcn_fdot2(dh, u2h(w1v.z), r6, false);
          r7 = __builtin_amdgcn_fdot2(dh, u2h(w1v.w), r7, false);
        }
      }
      float racc[8] = {r0,r1,r2,r3,r4,r5,r6,r7};
      if (valid) st8h(tab + (size_t)knot*256 + L*64 + c0, racc);
    }
    // pass 2: q[m] = sum_k dv[k]*W2[k][m]
    {
      uint4 av;
      av.x = pkh(dv[0],dv[1]); av.y = pkh(dv[2],dv[3]);
      av.z = pkh(dv[4],dv[5]); av.w = pkh(dv[6],dv[7]);
      *(uint4*)(myAh + 4*j) = av;
    }
    {
      float r0=0.f,r1=0.f,r2=0.f,r3=0.f,r4=0.f,r5=0.f,r6=0.f,r7=0.f;
      #pragma unroll 2
      for (int kp4=0; kp4<8; ++kp4){
        uint4 dq = *(const uint4*)(myAh + 4*kp4);
        #pragma unroll
        for (int i=0;i<4;++i){
          u32 du = (i==0)?dq.x:(i==1)?dq.y:(i==2)?dq.z:dq.w;
          f16x2 dh = u2h(du);
          const u32* wrow = w2h + (4*kp4+i)*64 + c0;
          uint4 w0 = *(const uint4*)(wrow);
          uint4 w1v = *(const uint4*)(wrow+4);
          r0 = __builtin_amdgcn_fdot2(dh, u2h(w0.x),  r0, false);
          r1 = __builtin_amdgcn_fdot2(dh, u2h(w0.y),  r1, false);
          r2 = __builtin_amdgcn_fdot2(dh, u2h(w0.z),  r2, false);
          r3 = __builtin_amdgcn_fdot2(dh, u2h(w0.w),  r3, false);
          r4 = __builtin_amdgcn_fdot2(dh, u2h(w1v.x), r4, false);
          r5 = __builtin_amdgcn_fdot2(dh, u2h(w1v.y), r5, false);
          r6 = __builtin_amdgcn_fdot2(dh, u2h(w1v.z), r6, false);
          r7 = __builtin_amdgcn_fdot2(dh, u2h(w1v.w), r7, false);
        }
      }
      float qacc[8] = {r0,r1,r2,r3,r4,r5,r6,r7};
      if (valid) st8h(tab + (size_t)knot*256 + 128 + L*64 + c0, qacc);
    }
  }
}

// ---------------- geometry only: Y(f16,l=1..8)/u3/irr/xi (1 thread per edge) ----------------
__global__ void k_fwd_edge(const float* __restrict__ pos, const float* __restrict__ shifts,
                const int* __restrict__ pe, const int* __restrict__ pSnd,
                const int* __restrict__ pRcv,
                u16* __restrict__ Y, float* __restrict__ u3,
                float* __restrict__ irr, float* __restrict__ xi){
  int e = blockIdx.x*256 + threadIdx.x;
  int eo  = pe[e];
  int snd = pSnd[e], rcv = pRcv[e];
  float vx = pos[snd*3+0]-pos[rcv*3+0]+shifts[(size_t)eo*3+0];
  float vy = pos[snd*3+1]-pos[rcv*3+1]+shifts[(size_t)eo*3+1];
  float vz = pos[snd*3+2]-pos[rcv*3+2]+shifts[(size_t)eo*3+2];
  float ss = vx*vx+vy*vy+vz*vz + 1e-12f;
  float rad = sqrtf(ss);
  float inv = 1.0f/rad;
  float x = vx*inv, y = vy*inv, z = vz*inv;
  irr[e]=inv;
  xi[e] = rad * ((float)TAB/RMAXF);
  u3[(size_t)e*3+0]=x; u3[(size_t)e*3+1]=y; u3[(size_t)e*3+2]=z;
  float Yf[8];
  Yf[0]=S3*x; Yf[1]=S3*y; Yf[2]=S3*z;
  Yf[3]=S15*x*y; Yf[4]=S15*y*z;
  Yf[5]=0.5f*S5*(3.0f*z*z-1.0f);
  Yf[6]=S15*x*z;
  Yf[7]=0.5f*S15*(x*x-y*y);
  st8h(Y + (size_t)e*8, Yf);
}

// ---------------- agg0[n,l,c]: contiguous rcv-range, R0 lerped, hu0 from attrs ----------------
__global__ void k_agg0(const int* __restrict__ offR, const int* __restrict__ pSnd,
                       const float* __restrict__ attrs, const float* __restrict__ WembUp,
                       const u16* __restrict__ tab, const float* __restrict__ xi,
                       const u16* __restrict__ Y,
                       u16* __restrict__ agg0){
  int t = threadIdx.x; int n = blockIdx.x*4 + (t>>6); int c = t&63;
  float we0 = WembUp[0*64+c], we1 = WembUp[1*64+c], we2 = WembUp[2*64+c], we3 = WembUp[3*64+c];
  float acc[9] = {0,0,0,0,0,0,0,0,0};
  int p0 = offR[n], p1 = offR[n+1];
  for (int p=p0;p<p1;++p){
    int s = pSnd[p];
    float xiv = xi[p];
    float r0v = 0.f;
    if (xiv < (float)TAB){
      int i0 = (int)xiv; float f = xiv - (float)i0;
      r0v = tlerp(tab, i0, f, c);
    }
    float4 av = *(const float4*)(attrs + (size_t)s*4);
    float hu0c = av.x*we0 + av.y*we1 + av.z*we2 + av.w*we3;
    float v = r0v*hu0c;
    float Yb[8];
    ldY(Y + (size_t)p*8, Yb);
    acc[0] += v;
    #pragma unroll
    for (int l=1;l<9;++l) acc[l] += Yb[l-1]*v;
  }
  #pragma unroll
  for (int l=0;l<9;++l) agg0[((size_t)n*9+l)*64+c] = f2h(acc[l]);
}

// ---------------- s1[p,c] = sum_l Y[p,l]*hu1[snd,l,c]  (snd-major) ----------------
__global__ void k_s1(const int* __restrict__ cntS, const int* __restrict__ listS,
                     const u16* __restrict__ hu1, const u16* __restrict__ Y,
                     u16* __restrict__ s1){
  int t = threadIdx.x; int n = blockIdx.x*4 + (t>>6); int c = t&63;
  float hu[9];
  #pragma unroll
  for (int l=0;l<9;++l) hu[l] = b2f(hu1[((size_t)n*9+l)*64+c]);
  int deg = min(cntS[n], CAP);
  #pragma unroll 2
  for (int j=0;j<deg;++j){
    int p = listS[n*CAP+j];
    float Yb[8];
    ldY(Y + (size_t)p*8, Yb);
    float acc = hu[0];
    #pragma unroll
    for (int l=1;l<9;++l) acc += hu[l]*Yb[l-1];
    s1[(size_t)p*64+c] = f2h(acc);
  }
}

// ---------------- agg1[n,c]: contiguous rcv-range, R1 lerped ----------------
__global__ void k_agg1(const int* __restrict__ offR,
                       const u16* __restrict__ tab, const float* __restrict__ xi,
                       const u16* __restrict__ s1,
                       float* __restrict__ agg1){
  int t = threadIdx.x; int n = blockIdx.x*4 + (t>>6); int c = t&63;
  float acc = 0.f;
  int p0 = offR[n], p1 = offR[n+1];
  for (int p=p0;p<p1;++p){
    float xiv = xi[p];
    float r1v = 0.f;
    if (xiv < (float)TAB){
      int i0 = (int)xiv; float f = xiv - (float)i0;
      r1v = tlerp(tab, i0, f, 64 + c);
    }
    acc += r1v*h2f(s1[(size_t)p*64+c]);
  }
  agg1[(size_t)n*64+c] = acc;
}

// ---------------- dhu1[n,l,c] = sum_{snd-list} Y[p,l]*R1(xi[p])[c]*ga1[rcv,c], out f16 ----------------
__global__ void k_dhu1(const int* __restrict__ cntS, const int* __restrict__ listS,
                       const int* __restrict__ pRcv,
                       const u16* __restrict__ tab, const float* __restrict__ xi,
                       const float* __restrict__ ga1, const u16* __restrict__ Y,
                       u16* __restrict__ dhu1){
  int t = threadIdx.x; int n = blockIdx.x*4 + (t>>6); int c = t&63;
  float acc[9] = {0,0,0,0,0,0,0,0,0};
  int deg = min(cntS[n], CAP);
  #pragma unroll 2
  for (int j=0;j<deg;++j){
    int p = listS[n*CAP+j];
    int r = pRcv[p];
    float xiv = xi[p];
    float r1v = 0.f;
    if (xiv < (float)TAB){
      int i0 = (int)xiv; float f = xiv - (float)i0;
      r1v = tlerp(tab, i0, f, 64 + c);
    }
    float ds = r1v*ga1[(size_t)r*64+c];
    float Yb[8];
    ldY(Y + (size_t)p*8, Yb);
    acc[0] += ds;
    #pragma unroll
    for (int l=1;l<9;++l) acc[l] += Yb[l-1]*ds;
  }
  #pragma unroll
  for (int l=0;l<9;++l) dhu1[((size_t)n*9+l)*64+c] = f2h(acc[l]);
}

// ---------------- 64x64 row-matmul (kept for dhu1->ga0) ----------------
template<bool TRANS, bool OUTB, bool IN16>
__global__ __launch_bounds__(256, 2)
void k_mm64(const void* __restrict__ in, const float* __restrict__ W,
            void* __restrict__ out, int rows, int lper,
            const float* __restrict__ attrs, const float* __restrict__ Wsk,
            const float* __restrict__ bias){
  __shared__ float sWT[64*68];
  __shared__ float sRow[4*68];
  int t = threadIdx.x;
  for (int i=t;i<4096;i+=256){
    int k=i&63, c=i>>6;
    sWT[c*68+k] = TRANS ? W[c*64+k] : W[k*64+c];
  }
  __syncthreads();
  int wid = t>>6, c = t&63;
  float wcol[64];
  {
    const float4* wp = (const float4*)(sWT + c*68);
    #pragma unroll
    for (int kk=0;kk<16;++kk){
      float4 w4 = wp[kk];
      wcol[4*kk+0]=w4.x; wcol[4*kk+1]=w4.y; wcol[4*kk+2]=w4.z; wcol[4*kk+3]=w4.w;
    }
  }
  float* myRow = sRow + wid*68;
  for (int it=0; it<8; ++it){
    int row = (blockIdx.x*8+it)*4 + wid;
    if (IN16) myRow[c] = h2f(((const u16*)in)[(size_t)row*64+c]);
    else      myRow[c] = ((const float*)in)[(size_t)row*64+c];
    float acc = 0.f;
    #pragma unroll
    for (int kk=0;kk<16;++kk){
      float4 r4 = ((const float4*)myRow)[kk];
      acc += r4.x*wcol[4*kk+0] + r4.y*wcol[4*kk+1] + r4.z*wcol[4*kk+2] + r4.w*wcol[4*kk+3];
    }
    if (lper==1 || (row % 9)==0){
      int n = (lper==1) ? row : (row/9);
      if (attrs){
        #pragma unroll
        for (int k=0;k<NE_;++k) acc += attrs[n*NE_+k]*Wsk[k*64+c];
      }
      if (bias) acc += bias[c];
    }
    if (OUTB) ((u16*)out)[(size_t)row*64+c] = f2b(acc);
    else      ((float*)out)[(size_t)row*64+c] = acc;
  }
}

// ---------------- agg0->hu1 matmul + FUSED read0/e0 ----------------
__global__ __launch_bounds__(256, 2)
void k_mm64_read0(const u16* __restrict__ in, const float* __restrict__ W,
                  u16* __restrict__ outB,
                  const float* __restrict__ attrs, const float* __restrict__ Wsk,
                  const float* __restrict__ va, const float* __restrict__ sv,
                  const float* __restrict__ ae, const int* __restrict__ batch,
                  float* __restrict__ out){
  __shared__ float sWT[64*68];
  __shared__ float sRow[4*68];
  __shared__ float bins0[G_];
  __shared__ float bins1[G_];
  int t = threadIdx.x;
  if (t < G_){ bins0[t]=0.f; bins1[t]=0.f; }
  for (int i=t;i<4096;i+=256){
    int k=i&63, c=i>>6;
    sWT[c*68+k] = W[k*64+c];
  }
  __syncthreads();
  int wid = t>>6, c = t&63;
  float vac = va[c];
  float wcol[64];
  {
    const float4* wp = (const float4*)(sWT + c*68);
    #pragma unroll
    for (int kk=0;kk<16;++kk){
      float4 w4 = wp[kk];
      wcol[4*kk+0]=w4.x; wcol[4*kk+1]=w4.y; wcol[4*kk+2]=w4.z; wcol[4*kk+3]=w4.w;
    }
  }
  float* myRow = sRow + wid*68;
  for (int it=0; it<8; ++it){
    int row = (blockIdx.x*8+it)*4 + wid;
    float rv = h2f(in[(size_t)row*64+c]);
    myRow[c] = rv;
    float acc = 0.f;
    #pragma unroll
    for (int kk=0;kk<16;++kk){
      float4 r4 = ((const float4*)myRow)[kk];
      acc += r4.x*wcol[4*kk+0] + r4.y*wcol[4*kk+1] + r4.z*wcol[4*kk+2] + r4.w*wcol[4*kk+3];
    }
    if ((row % 9)==0){
      int n = row/9;
      #pragma unroll
      for (int k=0;k<NE_;++k) acc += attrs[n*NE_+k]*Wsk[k*64+c];
      // fused read0: v = sum_c agg0row_l0[c]*va[c]
      float v = rv*vac;
      v += __shfl_xor(v,1,64);  v += __shfl_xor(v,2,64);
      v += __shfl_xor(v,4,64);  v += __shfl_xor(v,8,64);
      v += __shfl_xor(v,16,64); v += __shfl_xor(v,32,64);
      if (c==0){
        float4 av = *(const float4*)(attrs + (size_t)n*4);
        v += av.x*sv[0] + av.y*sv[1] + av.z*sv[2] + av.w*sv[3];
        float e0v = av.x*ae[0] + av.y*ae[1] + av.z*ae[2] + av.w*ae[3];
        int b = batch[n];
        atomicAdd(&bins1[b], v);
        atomicAdd(&bins0[b], e0v);
      }
    }
    outB[(size_t)row*64+c] = f2b(acc);
  }
  __syncthreads();
  if (t < G_){
    float b0 = bins0[t], b1 = bins1[t];
    if (b0 != 0.f || b1 != 0.f){
      atomicAdd(&out[t], b0 + b1);
      if (b0 != 0.f) atomicAdd(&out[G_ + t*3 + 0], b0);
      if (b1 != 0.f) atomicAdd(&out[G_ + t*3 + 1], b1);
    }
  }
}

// ---------------- agg1->h2 matmul + FUSED read1 + ga1 (h2 never materialized) ----------------
__global__ __launch_bounds__(256, 2)
void k_mm64_read1(const float* __restrict__ in, const float* __restrict__ W,
                  const float* __restrict__ attrs, const float* __restrict__ Wsk,
                  const float* __restrict__ Wr1, const float* __restrict__ wr2,
                  const float* __restrict__ CC, const int* __restrict__ batch,
                  float* __restrict__ ga1, float* __restrict__ out){
  __shared__ float sWT[64*68];
  __shared__ float sRow[4*68];
  __shared__ float sW[64*16];
  __shared__ float sCC[16*64];
  __shared__ float sH[4][64];
  __shared__ float sSp[4][16];
  __shared__ float sA[4][16];
  __shared__ float bins[G_];
  int t = threadIdx.x;
  if (t < G_) bins[t]=0.f;
  for (int i=t;i<4096;i+=256){
    int k=i&63, c=i>>6;
    sWT[c*68+k] = W[k*64+c];
  }
  for (int i=t;i<1024;i+=256){ sW[i]=Wr1[i]; sCC[i]=CC[i]; }
  __syncthreads();
  int wid = t>>6, c = t&63;
  float wcol[64];
  {
    const float4* wp = (const float4*)(sWT + c*68);
    #pragma unroll
    for (int kk=0;kk<16;++kk){
      float4 w4 = wp[kk];
      wcol[4*kk+0]=w4.x; wcol[4*kk+1]=w4.y; wcol[4*kk+2]=w4.z; wcol[4*kk+3]=w4.w;
    }
  }
  float* myRow = sRow + wid*68;
  for (int it=0; it<8; ++it){
    int n = (blockIdx.x*8+it)*4 + wid;
    myRow[c] = in[(size_t)n*64+c];
    float acc = 0.f;
    #pragma unroll
    for (int kk=0;kk<16;++kk){
      float4 r4 = ((const float4*)myRow)[kk];
      acc += r4.x*wcol[4*kk+0] + r4.y*wcol[4*kk+1] + r4.z*wcol[4*kk+2] + r4.w*wcol[4*kk+3];
    }
    #pragma unroll
    for (int k=0;k<NE_;++k) acc += attrs[n*NE_+k]*Wsk[k*64+c];
    // h2 row now lives across this wave's lanes; stage and do read1 in-block.
    sH[wid][c] = acc;
    __syncthreads();
    if (c < 16){
      float z = 0.f;
      const float* hr = sH[wid];
      #pragma unroll 16
      for (int k=0;k<64;++k) z += hr[k]*sW[k*16+c];
      float sg = sigmoidf_(z);
      float w2v = wr2[c];
      sSp[wid][c] = sg*(1.0f + z*(1.0f - sg))*w2v;
      sA[wid][c]  = z*sg*w2v;
    }
    __syncthreads();
    // ga1[n,c] = sum_j sSp[wid][j]*CC[j][c]
    {
      float g = 0.f;
      #pragma unroll
      for (int jp=0;jp<16;++jp) g += sSp[wid][jp]*sCC[jp*64+c];
      ga1[(size_t)n*64+c] = g;
    }
    if (c==0){
      float s = 0.f;
      #pragma unroll
      for (int k=0;k<16;++k) s += sA[wid][k];
      atomicAdd(&bins[batch[n]], s);
    }
    __syncthreads();
  }
  if (t < G_){
    float b = bins[t];
    if (b != 0.f){
      atomicAdd(&out[t], b);
      atomicAdd(&out[G_ + t*3 + 2], b);
    }
  }
}

// ---------------- fused per-edge backward: zero-LDS, table-lerped R/q, lazy hu0 ----------------
__global__ __launch_bounds__(256, 4)
void k_bedge_all(const int* __restrict__ pSnd, const int* __restrict__ pRcv,
             const u16* __restrict__ Y,
             const float* __restrict__ u3, const float* __restrict__ irr,
             const u16* __restrict__ tab, const float* __restrict__ xi,
             const float* __restrict__ ga1, const u16* __restrict__ ga0,
             const float* __restrict__ attrs, const float* __restrict__ WembUp,
             const u16* __restrict__ hu1,
             float* __restrict__ gF){
  int t = threadIdx.x;
  int wid=t>>6, lane=t&63, q=lane>>4, j=lane&15, c0=j*4;
  int slot = wid*4+q;
  int e = blockIdx.x*16 + slot;          // p-space: consecutive e share rcv
  int snd = pSnd[e], rcv = pRcv[e];
  // ---- issue layer-1 loads up front ----
  float Yl[9];
  Yl[0]=1.0f;
  ldY(Y + (size_t)e*8, Yl+1);
  ushort4 huv1[9];
  #pragma unroll
  for (int l=0;l<9;++l) huv1[l] = *(const ushort4*)(hu1 + ((size_t)snd*9 + l)*64 + c0);
  float T1[4];  ld4(ga1 + (size_t)rcv*64 + c0, T1);
  float4 av = *(const float4*)(attrs + (size_t)snd*4);
  float xiv = xi[e];
  // ---- lerp R0/R1/q0/q1 from the L2-resident table ----
  float R0v[4], R1v[4], q0v[4], q1v[4];
  if (xiv < (float)TAB){
    int i0 = (int)xiv; float f = xiv - (float)i0, g = 1.0f - f;
    const u16* ra = tab + (size_t)i0*256;
    const u16* rb = ra + 256;
    ushort4 a, b;
    a = *(const ushort4*)(ra + c0);        b = *(const ushort4*)(rb + c0);
    R0v[0]=h2f(a.x)*g+h2f(b.x)*f; R0v[1]=h2f(a.y)*g+h2f(b.y)*f;
    R0v[2]=h2f(a.z)*g+h2f(b.z)*f; R0v[3]=h2f(a.w)*g+h2f(b.w)*f;
    a = *(const ushort4*)(ra + 64 + c0);   b = *(const ushort4*)(rb + 64 + c0);
    R1v[0]=h2f(a.x)*g+h2f(b.x)*f; R1v[1]=h2f(a.y)*g+h2f(b.y)*f;
    R1v[2]=h2f(a.z)*g+h2f(b.z)*f; R1v[3]=h2f(a.w)*g+h2f(b.w)*f;
    a = *(const ushort4*)(ra + 128 + c0);  b = *(const ushort4*)(rb + 128 + c0);
    q0v[0]=h2f(a.x)*g+h2f(b.x)*f; q0v[1]=h2f(a.y)*g+h2f(b.y)*f;
    q0v[2]=h2f(a.z)*g+h2f(b.z)*f; q0v[3]=h2f(a.w)*g+h2f(b.w)*f;
    a = *(const ushort4*)(ra + 192 + c0);  b = *(const ushort4*)(rb + 192 + c0);
    q1v[0]=h2f(a.x)*g+h2f(b.x)*f; q1v[1]=h2f(a.y)*g+h2f(b.y)*f;
    q1v[2]=h2f(a.z)*g+h2f(b.z)*f; q1v[3]=h2f(a.w)*g+h2f(b.w)*f;
  } else {
    #pragma unroll
    for (int i=0;i<4;++i){ R0v[i]=0.f; R1v[i]=0.f; q0v[i]=0.f; q1v[i]=0.f; }
  }
  float dyp[9];
  // ---- layer 1: ds1 = R1*ga1[rcv]; sA = sum_l Y_l*hu1; dyp = ds1.hu ----
  float dR1[4];
  {
    float ds1[4], sA[4];
    #pragma unroll
    for (int i=0;i<4;++i){ ds1[i]=R1v[i]*T1[i]; sA[i]=0.f; }
    #pragma unroll
    for (int l=0;l<9;++l){
      float h0v=b2f(huv1[l].x), h1v=b2f(huv1[l].y), h2v=b2f(huv1[l].z), h3v=b2f(huv1[l].w);
      float Ylv = Yl[l];
      sA[0]+=h0v*Ylv; sA[1]+=h1v*Ylv; sA[2]+=h2v*Ylv; sA[3]+=h3v*Ylv;
      dyp[l] = ds1[0]*h0v + ds1[1]*h1v + ds1[2]*h2v + ds1[3]*h3v;
    }
    #pragma unroll
    for (int i=0;i<4;++i) dR1[i]=sA[i]*T1[i];
  }
  // ---- lazy hu0 (huv1 regs now dead): direct L1-hot WembUp reads ----
  float hu0v[4];
  #pragma unroll
  for (int i=0;i<4;++i)
    hu0v[i] = av.x*WembUp[0*64+c0+i] + av.y*WembUp[1*64+c0+i]
            + av.z*WembUp[2*64+c0+i] + av.w*WembUp[3*64+c0+i];
  // ---- layer 0: P = R0*hu0; T0 = sum_l Y_l*ga0; dyp += ga0.P ----
  float dR0[4];
  {
    ushort4 gv0[9];
    #pragma unroll
    for (int l=0;l<9;++l) gv0[l] = *(const ushort4*)(ga0 + ((size_t)rcv*9 + l)*64 + c0);
    float P[4], T0[4];
    #pragma unroll
    for (int i=0;i<4;++i){ P[i]=R0v[i]*hu0v[i]; T0[i]=0.f; }
    #pragma unroll
    for (int l=0;l<9;++l){
      float g0=b2f(gv0[l].x), g1=b2f(gv0[l].y), g2=b2f(gv0[l].z), g3=b2f(gv0[l].w);
      float Ylv = Yl[l];
      T0[0]+=g0*Ylv; T0[1]+=g1*Ylv; T0[2]+=g2*Ylv; T0[3]+=g3*Ylv;
      dyp[l] += g0*P[0] + g1*P[1] + g2*P[2] + g3*P[3];
    }
    #pragma unroll
    for (int i=0;i<4;++i) dR0[i]=hu0v[i]*T0[i];
  }
  // ---- dy reduction (16-lane groups) ----
  float dy[9];
  #pragma unroll
  for (int l=1;l<9;++l){
    float v=dyp[l];
    v += __shfl_xor(v,1,64); v += __shfl_xor(v,2,64);
    v += __shfl_xor(v,4,64); v += __shfl_xor(v,8,64);
    dy[l]=v;
  }
  // ---- dr = q1.dR1 + q0.dR0 (MLP backward fully folded into q) ----
  float dr = q1v[0]*dR1[0]+q1v[1]*dR1[1]+q1v[2]*dR1[2]+q1v[3]*dR1[3]
           + q0v[0]*dR0[0]+q0v[1]*dR0[1]+q0v[2]*dR0[2]+q0v[3]*dR0[3];
  dr += __shfl_xor(dr,1,64); dr += __shfl_xor(dr,2,64);
  dr += __shfl_xor(dr,4,64); dr += __shfl_xor(dr,8,64);
  // ---- SH backward epilogue + pure store ----
  float x = u3[(size_t)e*3+0], y = u3[(size_t)e*3+1], zz = u3[(size_t)e*3+2];
  float invr = irr[e];
  float dux = S3*dy[1] + S15*(y*dy[4] + zz*dy[7] + x*dy[8]);
  float duy = S3*dy[2] + S15*(x*dy[4] + zz*dy[5] - y*dy[8]);
  float duz = S3*dy[3] + S15*(y*dy[5] + x*dy[7]) + 3.0f*S5*zz*dy[6];
  float udot = x*dux + y*duy + zz*duz;
  float gx = dr*x + invr*(dux - x*udot);
  float gy = dr*y + invr*(duy - y*udot);
  float gz = dr*zz + invr*(duz - zz*udot);
  if (j==0){
    float* gp2 = gF + (size_t)e*3;
    gp2[0]=gx; gp2[1]=gy; gp2[2]=gz;
  }
}

// ---------------- node-major force gather: F[n] = sum_rcvRange g - sum_listS g ----------------
__global__ void k_fsum(const int* __restrict__ offR, const int* __restrict__ cntS,
                       const int* __restrict__ listS,
                       const float* __restrict__ gF, float* __restrict__ F){
  int t = threadIdx.x;
  int lane = t & 63, wid = t >> 6;
  int sub = lane >> 3, j = lane & 7;
  int n = blockIdx.x*32 + wid*8 + sub;
  float fx=0.f, fy=0.f, fz=0.f;
  int p0 = offR[n], p1 = offR[n+1];
  for (int p=p0+j; p<p1; p+=8){
    fx += gF[(size_t)p*3+0]; fy += gF[(size_t)p*3+1]; fz += gF[(size_t)p*3+2];
  }
  int dSn = min(cntS[n], CAP);
  for (int k=j;k<dSn;k+=8){
    int p = listS[n*CAP+k];
    fx -= gF[(size_t)p*3+0]; fy -= gF[(size_t)p*3+1]; fz -= gF[(size_t)p*3+2];
  }
  fx += __shfl_xor(fx,1,64); fy += __shfl_xor(fy,1,64); fz += __shfl_xor(fz,1,64);
  fx += __shfl_xor(fx,2,64); fy += __shfl_xor(fy,2,64); fz += __shfl_xor(fz,2,64);
  fx += __shfl_xor(fx,4,64); fy += __shfl_xor(fy,4,64); fz += __shfl_xor(fz,4,64);
  if (j==0){
    F[n*3+0]=fx; F[n*3+1]=fy; F[n*3+2]=fz;
  }
}

extern "C" void kernel_launch(void* const* d_in, const int* in_sizes, int n_in,
                              void* d_out, int out_size, void* d_ws, size_t ws_size,
                              hipStream_t stream){
  (void)in_sizes; (void)n_in;
  const float* pos    = (const float*)d_in[0];
  const float* attrs  = (const float*)d_in[1];
  const float* shifts = (const float*)d_in[2];
  const float* ae     = (const float*)d_in[3];
  const float* Wemb   = (const float*)d_in[4];
  const float* Wup    = (const float*)d_in[5];
  const float* W1     = (const float*)d_in[6];
  const float* W2     = (const float*)d_in[7];
  const float* Wout   = (const float*)d_in[8];
  const float* Wskip  = (const float*)d_in[9];
  const float* wread0 = (const float*)d_in[10];
  const float* Wr1    = (const float*)d_in[11];
  const float* wr2    = (const float*)d_in[12];
  const int*   ei     = (const int*)d_in[13];
  const int*   batch  = (const int*)d_in[14];
  float* out = (float*)d_out;

  const size_t NEED = 430000000;
  char* base;
  if (ws_size >= NEED){
    base = (char*)d_ws;
  } else {
    void* p = nullptr;
    hipGetSymbolAddress(&p, HIP_SYMBOL(g_fallback));
    base = (char*)p;
  }
  size_t off = 0;
  auto alloc = [&](size_t bytes)->char*{
    char* p = base + off;
    off += ((bytes + 255)/256)*256;
    return p;
  };
  u16*   Y    = (u16*)  alloc((size_t)E_*8*2);
  float* u3   = (float*)alloc((size_t)E_*3*4);
  float* irr  = (float*)alloc((size_t)E_*4);
  float* xi   = (float*)alloc((size_t)E_*4);
  u16*   s1b  = (u16*)  alloc((size_t)E_*64*2);
  float* gF   = (float*)alloc((size_t)E_*3*4);
  u16*   tab  = (u16*)  alloc((size_t)(TAB+1)*256*2);
  u16*   hu1  = (u16*)  alloc((size_t)N_*9*64*2);
  u16*   agg0 = (u16*)  alloc((size_t)N_*9*64*2);   // f16; reused as dhu1
  float* agg1 = (float*)alloc((size_t)N_*64*4);
  float* ga1  = (float*)alloc((size_t)N_*64*4);
  u16*   ga0  = (u16*)  alloc((size_t)N_*9*64*2);
  float* WembUp = (float*)alloc(256*4);
  float* WA   = (float*)alloc(4096*4);
  float* sa   = (float*)alloc(256*4);
  float* va   = (float*)alloc(64*4);
  float* sv   = (float*)alloc(4*4);
  float* CC   = (float*)alloc(1024*4);
  int* cnts  = (int*)alloc((size_t)3*N_*4);     // cntR | cntS | cntR2
  int* offR  = (int*)alloc((size_t)(N_+1)*4);
  int* pe    = (int*)alloc((size_t)E_*4);
  int* pSnd  = (int*)alloc((size_t)E_*4);
  int* pRcv  = (int*)alloc((size_t)E_*4);
  int* listS = (int*)alloc((size_t)N_*CAP*4);
  int* cntR = cnts;  int* cntS = cnts + N_;  int* cntR2 = cnts + 2*N_;
  u16* dhu1 = agg0;
  float* F = out + G_ + G_*3;

  hipMemsetAsync(d_out, 0, (size_t)out_size*sizeof(float), stream);
  hipMemsetAsync(cnts, 0, (size_t)3*N_*sizeof(int), stream);

  // edge renumbering (rcv-sorted dense p-space)
  k_cnt     <<<E_/256, 256, 0, stream>>>(ei, cntR);
  k_scan    <<<1, 256, 0, stream>>>(cntR, offR);
  k_perm    <<<E_/256, 256, 0, stream>>>(ei, offR, cntR2, cntS, pe, pSnd, pRcv, listS);

  // forward
  k_rtab    <<<(TAB+1+31)/32, 256, 0, stream>>>(W1, W2, tab);
  k_fwd_edge<<<E_/256, 256, 0, stream>>>(pos, shifts, pe, pSnd, pRcv, Y, u3, irr, xi);
  k_pre     <<<1, 256, 0, stream>>>(Wout, Wup + 4096, Wskip, wread0, Wemb, Wup, Wr1, Wout + 4096, WA, sa, va, sv, WembUp, CC);
  k_agg0    <<<N_/4, 256, 0, stream>>>(offR, pSnd, attrs, WembUp, tab, xi, Y, agg0);
  k_mm64_read0<<<N_*9/32, 256, 0, stream>>>(agg0, WA, hu1, attrs, sa, va, sv, ae, batch, out);
  k_s1      <<<N_/4, 256, 0, stream>>>(cntS, listS, hu1, Y, s1b);
  k_agg1    <<<N_/4, 256, 0, stream>>>(offR, tab, xi, s1b, agg1);
  k_mm64_read1<<<N_/32, 256, 0, stream>>>(agg1, Wout + 4096, attrs, Wskip + 256, Wr1, wr2, CC, batch, ga1, out);

  // backward
  k_dhu1    <<<N_/4, 256, 0, stream>>>(cntS, listS, pRcv, tab, xi, ga1, Y, dhu1);
  k_mm64<true,true,true><<<N_*9/32, 256, 0, stream>>>(dhu1, WA, ga0, N_*9, 9, nullptr, nullptr, va);
  k_bedge_all<<<E_/16, 256, 0, stream>>>(pSnd, pRcv, Y, u3, irr, tab, xi, ga1, ga0, attrs, WembUp, hu1, gF);
  k_fsum    <<<N_/32, 256, 0, stream>>>(offR, cntS, listS, gF, F);
}

// Round 14
// 726.893 us; speedup vs baseline: 1.0544x; 1.0544x over previous
//
#include <hip/hip_runtime.h>
#include <cmath>

constexpr int N_  = 20000;
constexpr int E_  = 320000;
constexpr int NE_ = 4;
constexpr int G_  = 16;
constexpr int CAP = 96;
constexpr int TAB = 4096;
constexpr float RMAXF = 5.0f;
constexpr float PI_F  = 3.14159265358979323846f;
constexpr float S3  = 1.7320508075688772f;
constexpr float S5  = 2.2360679774997896f;
constexpr float S15 = 3.8729833462074170f;
constexpr float KC_ = 0.6324555320336759f; // sqrt(2/RMAX)

typedef unsigned short u16;
typedef unsigned int   u32;
typedef _Float16 f16;
typedef _Float16 f16x2 __attribute__((ext_vector_type(2)));

#define DEV static __device__ __forceinline__

// fallback scratch (440 MB) in case ws_size is too small
__device__ float g_fallback[110000000];

DEV float sigmoidf_(float x){ return 1.0f/(1.0f+__expf(-x)); }

// bf16 <-> fp32 (RTNE pack)
DEV float b2f(u16 u){ return __uint_as_float(((u32)u)<<16); }
DEV u16  f2b(float f){
  u32 x = __float_as_uint(f);
  return (u16)((x + 0x7FFFu + ((x>>16)&1u)) >> 16);
}
// fp16 <-> fp32
DEV u16  f2h(float f){ union{f16 h; u16 u;} v; v.h=(f16)f; return v.u; }
DEV float h2f(u16 u){ union{u16 u2; f16 h;} v; v.u2=u; return (float)v.h; }

DEV f16x2 u2h(u32 x){ union{u32 u; f16x2 h;} v; v.u=x; return v.h; }
DEV u32 h2u(f16x2 h){ union{u32 u; f16x2 h;} v; v.h=h; return v.u; }
DEV u32 pkh(float a, float b){ f16x2 h; h.x=(f16)a; h.y=(f16)b; return h2u(h); }

DEV void ld4(const float* __restrict__ p, float* d){
  float4 a = ((const float4*)p)[0];
  d[0]=a.x; d[1]=a.y; d[2]=a.z; d[3]=a.w;
}
DEV void st8h(u16* p, const float* d){
  uint4 v;
  v.x = pkh(d[0],d[1]); v.y = pkh(d[2],d[3]);
  v.z = pkh(d[4],d[5]); v.w = pkh(d[6],d[7]);
  *(uint4*)p = v;
}
// load f16 Y row (l=1..8) into Yb[8]
DEV void ldY(const u16* __restrict__ p, float* Yb){
  ushort4 a = *(const ushort4*)p;
  ushort4 b = *(const ushort4*)(p+4);
  Yb[0]=h2f(a.x); Yb[1]=h2f(a.y); Yb[2]=h2f(a.z); Yb[3]=h2f(a.w);
  Yb[4]=h2f(b.x); Yb[5]=h2f(b.y); Yb[6]=h2f(b.z); Yb[7]=h2f(b.w);
}

// lerp one table entry (idx in [0,256)) at knot coordinate i0+f
DEV float tlerp(const u16* __restrict__ tab, int i0, float f, int idx){
  return h2f(tab[i0*256+idx])*(1.0f-f) + h2f(tab[(i0+1)*256+idx])*f;
}

// ---------------- edge renumbering: rcv-sorted dense p-space ----------------
__global__ void k_cnt(const int* __restrict__ ei, int* __restrict__ cntR){
  int e = blockIdx.x*256 + threadIdx.x;
  atomicAdd(&cntR[ei[E_+e]], 1);
}

__global__ void k_scan(const int* __restrict__ cntR, int* __restrict__ offR){
  __shared__ int part[256];
  int t = threadIdx.x;
  constexpr int CH = (N_+255)/256;
  int base = t*CH;
  int s=0;
  for (int i=0;i<CH;++i){ int idx=base+i; if(idx<N_) s+=cntR[idx]; }
  part[t]=s; __syncthreads();
  for (int d=1; d<256; d<<=1){
    int v = (t>=d)? part[t-d] : 0;
    __syncthreads();
    part[t]+=v;
    __syncthreads();
  }
  int run = (t==0)?0:part[t-1];
  for (int i=0;i<CH;++i){ int idx=base+i; if(idx<N_){ offR[idx]=run; run+=cntR[idx]; } }
  if (t==255) offR[N_]=run;
}

__global__ void k_perm(const int* __restrict__ ei, const int* __restrict__ offR,
                       int* __restrict__ cntR2, int* __restrict__ cntS,
                       int* __restrict__ pe, int* __restrict__ pSnd, int* __restrict__ pRcv,
                       int* __restrict__ listS){
  int e = blockIdx.x*256 + threadIdx.x;
  int s = ei[e], r = ei[E_+e];
  int p = offR[r] + atomicAdd(&cntR2[r], 1);
  pe[p] = e; pSnd[p] = s; pRcv[p] = r;
  int q = atomicAdd(&cntS[s], 1); if (q < CAP) listS[s*CAP+q] = p;
}

// ---------------- weight precompute: composite matrices + WembUp + CC ----------------
__global__ void k_pre(const float* __restrict__ Wout0, const float* __restrict__ Wup1,
                      const float* __restrict__ Wskip0, const float* __restrict__ wread0,
                      const float* __restrict__ Wemb, const float* __restrict__ Wup0,
                      const float* __restrict__ Wr1, const float* __restrict__ Wout1,
                      float* __restrict__ WA, float* __restrict__ sa,
                      float* __restrict__ va, float* __restrict__ sv,
                      float* __restrict__ WembUp, float* __restrict__ CC){
  int t = threadIdx.x;
  for (int idx=t; idx<4096; idx+=256){
    int c = idx>>6, d = idx&63;
    float acc=0.f;
    for (int m=0;m<64;++m) acc += Wout0[c*64+m]*Wup1[m*64+d];
    WA[idx]=acc;
  }
  {
    int k = t>>6, d = t&63;
    float acc=0.f;
    for (int m=0;m<64;++m) acc += Wskip0[k*64+m]*Wup1[m*64+d];
    sa[t]=acc;
    float acc2=0.f;
    for (int j=0;j<64;++j) acc2 += Wemb[k*64+j]*Wup0[j*64+d];
    WembUp[t]=acc2;
  }
  // CC[j*64+c] = sum_k Wr1[k*16+j]*Wout1[c*64+k]   (folds dh2+ga1 matmuls)
  for (int idx=t; idx<1024; idx+=256){
    int j = idx>>6, c = idx&63;
    float acc=0.f;
    for (int k=0;k<64;++k) acc += Wr1[k*16+j]*Wout1[c*64+k];
    CC[idx]=acc;
  }
  if (t<64){
    float acc=0.f;
    for (int d=0;d<64;++d) acc += Wout0[t*64+d]*wread0[d];
    va[t]=acc;
  }
  if (t<4){
    float acc=0.f;
    for (int d=0;d<64;++d) acc += Wskip0[t*64+d]*wread0[d];
    sv[t]=acc;
  }
}

// ---------------- radial table build: tab[i][256] = [R0|R1|q0|q1](r_i), f16 ----------------
__global__ __launch_bounds__(256, 2)
void k_rtab(const float* __restrict__ W1g, const float* __restrict__ W2g,
            u16* __restrict__ tab){
  __shared__ float sW1[1024];   // [layer][8][64]
  __shared__ u32   sW2h[4096];  // [layer][32 kp][64 c]
  __shared__ u32   sAh[32*36];
  int t = threadIdx.x;
  for (int i=t;i<1024;i+=256) sW1[i]=W1g[i];
  for (int i=t;i<4096;i+=256){
    int L = i>>11, rem = i&2047, kp = rem>>6, c = rem&63;
    sW2h[i] = pkh(W2g[L*4096 + (2*kp)*64 + c], W2g[L*4096 + (2*kp+1)*64 + c]);
  }
  __syncthreads();
  int wid=t>>6, lane=t&63, q=lane>>3, j=lane&7, c0=j*8;
  int slot = wid*8 + q;
  int knot = blockIdx.x*32 + slot;
  bool valid = (knot <= TAB);
  float rad = fmaxf((float)knot * (RMAXF/(float)TAB), 1e-6f);
  float inv = 1.0f/rad;
  float tt = rad*(1.0f/RMAXF);
  float fc = 0.0f, dfc = 0.0f;
  if (tt < 1.0f){
    float t2=tt*tt, t4=t2*t2, t5=t4*tt, t6=t5*tt, t7=t6*tt, t8=t7*tt;
    fc  = 1.0f - 28.0f*t6 + 48.0f*t7 - 21.0f*t8;
    dfc = (-168.0f*t5 + 336.0f*t6 - 168.0f*t7)*(1.0f/RMAXF);
  }
  float th = rad*(PI_F/RMAXF);
  float s1 = __sinf(th), c1 = __cosf(th);
  float base = KC_*inv*fc;
  float efv[8], gfv[8];
  {
    float sb = s1, cb = c1;
    #pragma unroll
    for (int b=0;b<8;++b){
      efv[b] = base*sb;
      float wb_ = (float)(b+1)*(PI_F/RMAXF);
      float rb  = KC_*sb*inv;
      float drb = KC_*(wb_*cb - sb*inv)*inv;
      gfv[b] = drb*fc + rb*dfc;
      float sn = sb*c1 + cb*s1;
      cb = cb*c1 - sb*s1;
      sb = sn;
    }
  }
  u32* myAh = sAh + slot*36;
  for (int L=0; L<2; ++L){
    const float* w1 = sW1 + L*512;
    const u32*  w2h = sW2h + L*2048;
    float zz[8]={0,0,0,0,0,0,0,0};
    float wgv[8]={0,0,0,0,0,0,0,0};
    #pragma unroll 4
    for (int b=0;b<8;++b){
      float efb = efv[b], gfb = gfv[b];
      const float4* w=(const float4*)(w1 + b*64 + c0);
      float4 wa=w[0], wb=w[1];
      zz[0]+=efb*wa.x; zz[1]+=efb*wa.y; zz[2]+=efb*wa.z; zz[3]+=efb*wa.w;
      zz[4]+=efb*wb.x; zz[5]+=efb*wb.y; zz[6]+=efb*wb.z; zz[7]+=efb*wb.w;
      wgv[0]+=gfb*wa.x; wgv[1]+=gfb*wa.y; wgv[2]+=gfb*wa.z; wgv[3]+=gfb*wa.w;
      wgv[4]+=gfb*wb.x; wgv[5]+=gfb*wb.y; wgv[6]+=gfb*wb.z; wgv[7]+=gfb*wb.w;
    }
    float a[8], dv[8];
    #pragma unroll
    for (int i=0;i<8;++i){
      float sg = sigmoidf_(zz[i]);
      a[i]  = zz[i]*sg;
      float sp = sg*(1.0f + zz[i]*(1.0f - sg));
      dv[i] = wgv[i]*sp;
    }
    // pass 1: R[c] = sum_k a[k]*W2[k][c]
    {
      uint4 av;
      av.x = pkh(a[0],a[1]); av.y = pkh(a[2],a[3]);
      av.z = pkh(a[4],a[5]); av.w = pkh(a[6],a[7]);
      *(uint4*)(myAh + 4*j) = av;
    }
    {
      float r0=0.f,r1=0.f,r2=0.f,r3=0.f,r4=0.f,r5=0.f,r6=0.f,r7=0.f;
      #pragma unroll 2
      for (int kp4=0; kp4<8; ++kp4){
        uint4 dq = *(const uint4*)(myAh + 4*kp4);
        #pragma unroll
        for (int i=0;i<4;++i){
          u32 du = (i==0)?dq.x:(i==1)?dq.y:(i==2)?dq.z:dq.w;
          f16x2 dh = u2h(du);
          const u32* wrow = w2h + (4*kp4+i)*64 + c0;
          uint4 w0 = *(const uint4*)(wrow);
          uint4 w1v = *(const uint4*)(wrow+4);
          r0 = __builtin_amdgcn_fdot2(dh, u2h(w0.x),  r0, false);
          r1 = __builtin_amdgcn_fdot2(dh, u2h(w0.y),  r1, false);
          r2 = __builtin_amdgcn_fdot2(dh, u2h(w0.z),  r2, false);
          r3 = __builtin_amdgcn_fdot2(dh, u2h(w0.w),  r3, false);
          r4 = __builtin_amdgcn_fdot2(dh, u2h(w1v.x), r4, false);
          r5 = __builtin_amdgcn_fdot2(dh, u2h(w1v.y), r5, false);
          r6 = __builtin_amdgcn_fdot2(dh, u2h(w1v.z), r6, false);
          r7 = __builtin_amdgcn_fdot2(dh, u2h(w1v.w), r7, false);
        }
      }
      float racc[8] = {r0,r1,r2,r3,r4,r5,r6,r7};
      if (valid) st8h(tab + (size_t)knot*256 + L*64 + c0, racc);
    }
    // pass 2: q[m] = sum_k dv[k]*W2[k][m]
    {
      uint4 av;
      av.x = pkh(dv[0],dv[1]); av.y = pkh(dv[2],dv[3]);
      av.z = pkh(dv[4],dv[5]); av.w = pkh(dv[6],dv[7]);
      *(uint4*)(myAh + 4*j) = av;
    }
    {
      float r0=0.f,r1=0.f,r2=0.f,r3=0.f,r4=0.f,r5=0.f,r6=0.f,r7=0.f;
      #pragma unroll 2
      for (int kp4=0; kp4<8; ++kp4){
        uint4 dq = *(const uint4*)(myAh + 4*kp4);
        #pragma unroll
        for (int i=0;i<4;++i){
          u32 du = (i==0)?dq.x:(i==1)?dq.y:(i==2)?dq.z:dq.w;
          f16x2 dh = u2h(du);
          const u32* wrow = w2h + (4*kp4+i)*64 + c0;
          uint4 w0 = *(const uint4*)(wrow);
          uint4 w1v = *(const uint4*)(wrow+4);
          r0 = __builtin_amdgcn_fdot2(dh, u2h(w0.x),  r0, false);
          r1 = __builtin_amdgcn_fdot2(dh, u2h(w0.y),  r1, false);
          r2 = __builtin_amdgcn_fdot2(dh, u2h(w0.z),  r2, false);
          r3 = __builtin_amdgcn_fdot2(dh, u2h(w0.w),  r3, false);
          r4 = __builtin_amdgcn_fdot2(dh, u2h(w1v.x), r4, false);
          r5 = __builtin_amdgcn_fdot2(dh, u2h(w1v.y), r5, false);
          r6 = __builtin_amdgcn_fdot2(dh, u2h(w1v.z), r6, false);
          r7 = __builtin_amdgcn_fdot2(dh, u2h(w1v.w), r7, false);
        }
      }
      float qacc[8] = {r0,r1,r2,r3,r4,r5,r6,r7};
      if (valid) st8h(tab + (size_t)knot*256 + 128 + L*64 + c0, qacc);
    }
  }
}

// ---------------- geometry only: Y(f16,l=1..8)/u3/irr/xi (1 thread per edge) ----------------
__global__ void k_fwd_edge(const float* __restrict__ pos, const float* __restrict__ shifts,
                const int* __restrict__ pe, const int* __restrict__ pSnd,
                const int* __restrict__ pRcv,
                u16* __restrict__ Y, float* __restrict__ u3,
                float* __restrict__ irr, float* __restrict__ xi){
  int e = blockIdx.x*256 + threadIdx.x;
  int eo  = pe[e];
  int snd = pSnd[e], rcv = pRcv[e];
  float vx = pos[snd*3+0]-pos[rcv*3+0]+shifts[(size_t)eo*3+0];
  float vy = pos[snd*3+1]-pos[rcv*3+1]+shifts[(size_t)eo*3+1];
  float vz = pos[snd*3+2]-pos[rcv*3+2]+shifts[(size_t)eo*3+2];
  float ss = vx*vx+vy*vy+vz*vz + 1e-12f;
  float rad = sqrtf(ss);
  float inv = 1.0f/rad;
  float x = vx*inv, y = vy*inv, z = vz*inv;
  irr[e]=inv;
  xi[e] = rad * ((float)TAB/RMAXF);
  u3[(size_t)e*3+0]=x; u3[(size_t)e*3+1]=y; u3[(size_t)e*3+2]=z;
  float Yf[8];
  Yf[0]=S3*x; Yf[1]=S3*y; Yf[2]=S3*z;
  Yf[3]=S15*x*y; Yf[4]=S15*y*z;
  Yf[5]=0.5f*S5*(3.0f*z*z-1.0f);
  Yf[6]=S15*x*z;
  Yf[7]=0.5f*S15*(x*x-y*y);
  st8h(Y + (size_t)e*8, Yf);
}

// ---------------- agg0[n,l,c]: contiguous rcv-range, R0 lerped, hu0 from attrs ----------------
__global__ void k_agg0(const int* __restrict__ offR, const int* __restrict__ pSnd,
                       const float* __restrict__ attrs, const float* __restrict__ WembUp,
                       const u16* __restrict__ tab, const float* __restrict__ xi,
                       const u16* __restrict__ Y,
                       u16* __restrict__ agg0){
  int t = threadIdx.x; int n = blockIdx.x*4 + (t>>6); int c = t&63;
  float we0 = WembUp[0*64+c], we1 = WembUp[1*64+c], we2 = WembUp[2*64+c], we3 = WembUp[3*64+c];
  float acc[9] = {0,0,0,0,0,0,0,0,0};
  int p0 = offR[n], p1 = offR[n+1];
  for (int p=p0;p<p1;++p){
    int s = pSnd[p];
    float xiv = xi[p];
    float r0v = 0.f;
    if (xiv < (float)TAB){
      int i0 = (int)xiv; float f = xiv - (float)i0;
      r0v = tlerp(tab, i0, f, c);
    }
    float4 av = *(const float4*)(attrs + (size_t)s*4);
    float hu0c = av.x*we0 + av.y*we1 + av.z*we2 + av.w*we3;
    float v = r0v*hu0c;
    float Yb[8];
    ldY(Y + (size_t)p*8, Yb);
    acc[0] += v;
    #pragma unroll
    for (int l=1;l<9;++l) acc[l] += Yb[l-1]*v;
  }
  #pragma unroll
  for (int l=0;l<9;++l) agg0[((size_t)n*9+l)*64+c] = f2h(acc[l]);
}

// ---------------- s1[p,c] = sum_l Y[p,l]*hu1[snd,l,c]  (snd-major) ----------------
__global__ void k_s1(const int* __restrict__ cntS, const int* __restrict__ listS,
                     const u16* __restrict__ hu1, const u16* __restrict__ Y,
                     u16* __restrict__ s1){
  int t = threadIdx.x; int n = blockIdx.x*4 + (t>>6); int c = t&63;
  float hu[9];
  #pragma unroll
  for (int l=0;l<9;++l) hu[l] = b2f(hu1[((size_t)n*9+l)*64+c]);
  int deg = min(cntS[n], CAP);
  #pragma unroll 2
  for (int j=0;j<deg;++j){
    int p = listS[n*CAP+j];
    float Yb[8];
    ldY(Y + (size_t)p*8, Yb);
    float acc = hu[0];
    #pragma unroll
    for (int l=1;l<9;++l) acc += hu[l]*Yb[l-1];
    s1[(size_t)p*64+c] = f2h(acc);
  }
}

// ---------------- agg1[n,c]: contiguous rcv-range, R1 lerped ----------------
__global__ void k_agg1(const int* __restrict__ offR,
                       const u16* __restrict__ tab, const float* __restrict__ xi,
                       const u16* __restrict__ s1,
                       float* __restrict__ agg1){
  int t = threadIdx.x; int n = blockIdx.x*4 + (t>>6); int c = t&63;
  float acc = 0.f;
  int p0 = offR[n], p1 = offR[n+1];
  for (int p=p0;p<p1;++p){
    float xiv = xi[p];
    float r1v = 0.f;
    if (xiv < (float)TAB){
      int i0 = (int)xiv; float f = xiv - (float)i0;
      r1v = tlerp(tab, i0, f, 64 + c);
    }
    acc += r1v*h2f(s1[(size_t)p*64+c]);
  }
  agg1[(size_t)n*64+c] = acc;
}

// ---------------- dhu1[n,l,c] = sum_{snd-list} Y[p,l]*R1(xi[p])[c]*ga1[rcv,c], out f16 ----------------
__global__ void k_dhu1(const int* __restrict__ cntS, const int* __restrict__ listS,
                       const int* __restrict__ pRcv,
                       const u16* __restrict__ tab, const float* __restrict__ xi,
                       const float* __restrict__ ga1, const u16* __restrict__ Y,
                       u16* __restrict__ dhu1){
  int t = threadIdx.x; int n = blockIdx.x*4 + (t>>6); int c = t&63;
  float acc[9] = {0,0,0,0,0,0,0,0,0};
  int deg = min(cntS[n], CAP);
  #pragma unroll 2
  for (int j=0;j<deg;++j){
    int p = listS[n*CAP+j];
    int r = pRcv[p];
    float xiv = xi[p];
    float r1v = 0.f;
    if (xiv < (float)TAB){
      int i0 = (int)xiv; float f = xiv - (float)i0;
      r1v = tlerp(tab, i0, f, 64 + c);
    }
    float ds = r1v*ga1[(size_t)r*64+c];
    float Yb[8];
    ldY(Y + (size_t)p*8, Yb);
    acc[0] += ds;
    #pragma unroll
    for (int l=1;l<9;++l) acc[l] += Yb[l-1]*ds;
  }
  #pragma unroll
  for (int l=0;l<9;++l) dhu1[((size_t)n*9+l)*64+c] = f2h(acc[l]);
}

// ---------------- 64x64 row-matmul (IN16: f16 input rows) ----------------
template<bool TRANS, bool OUTB, bool IN16>
__global__ __launch_bounds__(256, 2)
void k_mm64(const void* __restrict__ in, const float* __restrict__ W,
            void* __restrict__ out, int rows, int lper,
            const float* __restrict__ attrs, const float* __restrict__ Wsk,
            const float* __restrict__ bias){
  __shared__ float sWT[64*68];
  __shared__ float sRow[4*68];
  int t = threadIdx.x;
  for (int i=t;i<4096;i+=256){
    int k=i&63, c=i>>6;
    sWT[c*68+k] = TRANS ? W[c*64+k] : W[k*64+c];
  }
  __syncthreads();
  int wid = t>>6, c = t&63;
  float wcol[64];
  {
    const float4* wp = (const float4*)(sWT + c*68);
    #pragma unroll
    for (int kk=0;kk<16;++kk){
      float4 w4 = wp[kk];
      wcol[4*kk+0]=w4.x; wcol[4*kk+1]=w4.y; wcol[4*kk+2]=w4.z; wcol[4*kk+3]=w4.w;
    }
  }
  float* myRow = sRow + wid*68;
  for (int it=0; it<8; ++it){
    int row = (blockIdx.x*8+it)*4 + wid;
    if (IN16) myRow[c] = h2f(((const u16*)in)[(size_t)row*64+c]);
    else      myRow[c] = ((const float*)in)[(size_t)row*64+c];
    float acc = 0.f;
    #pragma unroll
    for (int kk=0;kk<16;++kk){
      float4 r4 = ((const float4*)myRow)[kk];
      acc += r4.x*wcol[4*kk+0] + r4.y*wcol[4*kk+1] + r4.z*wcol[4*kk+2] + r4.w*wcol[4*kk+3];
    }
    if (lper==1 || (row % 9)==0){
      int n = (lper==1) ? row : (row/9);
      if (attrs){
        #pragma unroll
        for (int k=0;k<NE_;++k) acc += attrs[n*NE_+k]*Wsk[k*64+c];
      }
      if (bias) acc += bias[c];
    }
    if (OUTB) ((u16*)out)[(size_t)row*64+c] = f2b(acc);
    else      ((float*)out)[(size_t)row*64+c] = acc;
  }
}

// ---------------- readout 0 (+ folded e0) ----------------
__global__ void k_read0(const u16* __restrict__ agg0, const float* __restrict__ va,
                        const float* __restrict__ sv, const float* __restrict__ attrs,
                        const float* __restrict__ ae,
                        const int* __restrict__ batch, float* __restrict__ out){
  __shared__ float bins0[G_];
  __shared__ float bins1[G_];
  int t = threadIdx.x;
  if (t < G_){ bins0[t] = 0.f; bins1[t] = 0.f; }
  __syncthreads();
  int lane = t & 63, wid = t >> 6;
  int grp = lane >> 3, j = lane & 7;
  int n = blockIdx.x*32 + wid*8 + grp;
  const u16* hp = agg0 + (size_t)n*576 + j*8;
  float h[8];
  ldY(hp, h);   // 8 f16 loads (row l=0 slice)
  const float* wp = va + j*8;
  float4 w0v = ((const float4*)wp)[0], w4v = ((const float4*)wp)[1];
  float v = h[0]*w0v.x + h[1]*w0v.y + h[2]*w0v.z + h[3]*w0v.w
          + h[4]*w4v.x + h[5]*w4v.y + h[6]*w4v.z + h[7]*w4v.w;
  v += __shfl_xor(v,1,64); v += __shfl_xor(v,2,64); v += __shfl_xor(v,4,64);
  if (j==0){
    float4 av = *(const float4*)(attrs + (size_t)n*4);
    v += av.x*sv[0] + av.y*sv[1] + av.z*sv[2] + av.w*sv[3];
    float e0v = av.x*ae[0] + av.y*ae[1] + av.z*ae[2] + av.w*ae[3];
    int b = batch[n];
    atomicAdd(&bins1[b], v);
    atomicAdd(&bins0[b], e0v);
  }
  __syncthreads();
  if (t < G_){
    float b0 = bins0[t], b1 = bins1[t];
    if (b0 != 0.f || b1 != 0.f){
      atomicAdd(&out[t], b0 + b1);
      if (b0 != 0.f) atomicAdd(&out[G_ + t*3 + 0], b0);
      if (b1 != 0.f) atomicAdd(&out[G_ + t*3 + 1], b1);
    }
  }
}

// ---------------- readout 1 + fused ga1 (via CC composite) ----------------
__global__ void k_read1(const float* __restrict__ h2, const float* __restrict__ Wr1,
                        const float* __restrict__ wr2, const int* __restrict__ batch,
                        const float* __restrict__ CC,
                        float* __restrict__ ga1, float* __restrict__ out){
  __shared__ float sW[64*16];
  __shared__ float sCC[16*64];
  __shared__ float sSp[256];
  __shared__ float sA[256];
  __shared__ float bins[G_];
  int t = threadIdx.x;
  for (int i=t;i<1024;i+=256){ sW[i]=Wr1[i]; sCC[i]=CC[i]; }
  if (t < G_) bins[t] = 0.f;
  __syncthreads();
  int nn = t>>4; int j = t&15;
  int n = blockIdx.x*16 + nn;
  float z = 0.f;
  #pragma unroll 16
  for (int c=0;c<64;++c) z += h2[(size_t)n*64+c]*sW[c*16+j];
  float sg = sigmoidf_(z);
  float a  = z*sg;
  float sp = sg*(1.0f + z*(1.0f - sg));
  float w2v = wr2[j];
  sSp[t] = sp*w2v;
  sA[t]  = a*w2v;
  __syncthreads();
  // ga1[n, j*4 .. j*4+3] = sum_j' spz[n,j'] * CC[j'][c]
  {
    int cb = j*4;
    float g0=0.f,g1=0.f,g2=0.f,g3=0.f;
    const float* sp_ = sSp + nn*16;
    #pragma unroll
    for (int jp=0;jp<16;++jp){
      float s = sp_[jp];
      const float* cc = sCC + jp*64 + cb;
      g0 += s*cc[0]; g1 += s*cc[1]; g2 += s*cc[2]; g3 += s*cc[3];
    }
    *(float4*)(ga1 + (size_t)n*64 + cb) = make_float4(g0,g1,g2,g3);
  }
  if (j==0){
    float s = 0.f;
    #pragma unroll
    for (int k=0;k<16;++k) s += sA[nn*16+k];
    atomicAdd(&bins[batch[n]], s);
  }
  __syncthreads();
  if (t < G_){
    float b = bins[t];
    if (b != 0.f){
      atomicAdd(&out[t], b);
      atomicAdd(&out[G_ + t*3 + 2], b);
    }
  }
}

// ---------------- fused per-edge backward: zero-LDS, table-lerped R/q, lazy hu0 ----------------
__global__ __launch_bounds__(256, 4)
void k_bedge_all(const int* __restrict__ pSnd, const int* __restrict__ pRcv,
             const u16* __restrict__ Y,
             const float* __restrict__ u3, const float* __restrict__ irr,
             const u16* __restrict__ tab, const float* __restrict__ xi,
             const float* __restrict__ ga1, const u16* __restrict__ ga0,
             const float* __restrict__ attrs, const float* __restrict__ WembUp,
             const u16* __restrict__ hu1,
             float* __restrict__ gF){
  int t = threadIdx.x;
  int wid=t>>6, lane=t&63, q=lane>>4, j=lane&15, c0=j*4;
  int slot = wid*4+q;
  int e = blockIdx.x*16 + slot;          // p-space: consecutive e share rcv
  int snd = pSnd[e], rcv = pRcv[e];
  // ---- issue layer-1 loads up front ----
  float Yl[9];
  Yl[0]=1.0f;
  ldY(Y + (size_t)e*8, Yl+1);
  ushort4 huv1[9];
  #pragma unroll
  for (int l=0;l<9;++l) huv1[l] = *(const ushort4*)(hu1 + ((size_t)snd*9 + l)*64 + c0);
  float T1[4];  ld4(ga1 + (size_t)rcv*64 + c0, T1);
  float4 av = *(const float4*)(attrs + (size_t)snd*4);
  float xiv = xi[e];
  // ---- lerp R0/R1/q0/q1 from the L2-resident table ----
  float R0v[4], R1v[4], q0v[4], q1v[4];
  if (xiv < (float)TAB){
    int i0 = (int)xiv; float f = xiv - (float)i0, g = 1.0f - f;
    const u16* ra = tab + (size_t)i0*256;
    const u16* rb = ra + 256;
    ushort4 a, b;
    a = *(const ushort4*)(ra + c0);        b = *(const ushort4*)(rb + c0);
    R0v[0]=h2f(a.x)*g+h2f(b.x)*f; R0v[1]=h2f(a.y)*g+h2f(b.y)*f;
    R0v[2]=h2f(a.z)*g+h2f(b.z)*f; R0v[3]=h2f(a.w)*g+h2f(b.w)*f;
    a = *(const ushort4*)(ra + 64 + c0);   b = *(const ushort4*)(rb + 64 + c0);
    R1v[0]=h2f(a.x)*g+h2f(b.x)*f; R1v[1]=h2f(a.y)*g+h2f(b.y)*f;
    R1v[2]=h2f(a.z)*g+h2f(b.z)*f; R1v[3]=h2f(a.w)*g+h2f(b.w)*f;
    a = *(const ushort4*)(ra + 128 + c0);  b = *(const ushort4*)(rb + 128 + c0);
    q0v[0]=h2f(a.x)*g+h2f(b.x)*f; q0v[1]=h2f(a.y)*g+h2f(b.y)*f;
    q0v[2]=h2f(a.z)*g+h2f(b.z)*f; q0v[3]=h2f(a.w)*g+h2f(b.w)*f;
    a = *(const ushort4*)(ra + 192 + c0);  b = *(const ushort4*)(rb + 192 + c0);
    q1v[0]=h2f(a.x)*g+h2f(b.x)*f; q1v[1]=h2f(a.y)*g+h2f(b.y)*f;
    q1v[2]=h2f(a.z)*g+h2f(b.z)*f; q1v[3]=h2f(a.w)*g+h2f(b.w)*f;
  } else {
    #pragma unroll
    for (int i=0;i<4;++i){ R0v[i]=0.f; R1v[i]=0.f; q0v[i]=0.f; q1v[i]=0.f; }
  }
  float dyp[9];
  // ---- layer 1: ds1 = R1*ga1[rcv]; sA = sum_l Y_l*hu1; dyp = ds1.hu ----
  float dR1[4];
  {
    float ds1[4], sA[4];
    #pragma unroll
    for (int i=0;i<4;++i){ ds1[i]=R1v[i]*T1[i]; sA[i]=0.f; }
    #pragma unroll
    for (int l=0;l<9;++l){
      float h0v=b2f(huv1[l].x), h1v=b2f(huv1[l].y), h2v=b2f(huv1[l].z), h3v=b2f(huv1[l].w);
      float Ylv = Yl[l];
      sA[0]+=h0v*Ylv; sA[1]+=h1v*Ylv; sA[2]+=h2v*Ylv; sA[3]+=h3v*Ylv;
      dyp[l] = ds1[0]*h0v + ds1[1]*h1v + ds1[2]*h2v + ds1[3]*h3v;
    }
    #pragma unroll
    for (int i=0;i<4;++i) dR1[i]=sA[i]*T1[i];
  }
  // ---- lazy hu0 (huv1 regs now dead): direct L1-hot WembUp reads ----
  float hu0v[4];
  #pragma unroll
  for (int i=0;i<4;++i)
    hu0v[i] = av.x*WembUp[0*64+c0+i] + av.y*WembUp[1*64+c0+i]
            + av.z*WembUp[2*64+c0+i] + av.w*WembUp[3*64+c0+i];
  // ---- layer 0: P = R0*hu0; T0 = sum_l Y_l*ga0; dyp += ga0.P ----
  float dR0[4];
  {
    ushort4 gv0[9];
    #pragma unroll
    for (int l=0;l<9;++l) gv0[l] = *(const ushort4*)(ga0 + ((size_t)rcv*9 + l)*64 + c0);
    float P[4], T0[4];
    #pragma unroll
    for (int i=0;i<4;++i){ P[i]=R0v[i]*hu0v[i]; T0[i]=0.f; }
    #pragma unroll
    for (int l=0;l<9;++l){
      float g0=b2f(gv0[l].x), g1=b2f(gv0[l].y), g2=b2f(gv0[l].z), g3=b2f(gv0[l].w);
      float Ylv = Yl[l];
      T0[0]+=g0*Ylv; T0[1]+=g1*Ylv; T0[2]+=g2*Ylv; T0[3]+=g3*Ylv;
      dyp[l] += g0*P[0] + g1*P[1] + g2*P[2] + g3*P[3];
    }
    #pragma unroll
    for (int i=0;i<4;++i) dR0[i]=hu0v[i]*T0[i];
  }
  // ---- dy reduction (16-lane groups) ----
  float dy[9];
  #pragma unroll
  for (int l=1;l<9;++l){
    float v=dyp[l];
    v += __shfl_xor(v,1,64); v += __shfl_xor(v,2,64);
    v += __shfl_xor(v,4,64); v += __shfl_xor(v,8,64);
    dy[l]=v;
  }
  // ---- dr = q1.dR1 + q0.dR0 (MLP backward fully folded into q) ----
  float dr = q1v[0]*dR1[0]+q1v[1]*dR1[1]+q1v[2]*dR1[2]+q1v[3]*dR1[3]
           + q0v[0]*dR0[0]+q0v[1]*dR0[1]+q0v[2]*dR0[2]+q0v[3]*dR0[3];
  dr += __shfl_xor(dr,1,64); dr += __shfl_xor(dr,2,64);
  dr += __shfl_xor(dr,4,64); dr += __shfl_xor(dr,8,64);
  // ---- SH backward epilogue + pure store ----
  float x = u3[(size_t)e*3+0], y = u3[(size_t)e*3+1], zz = u3[(size_t)e*3+2];
  float invr = irr[e];
  float dux = S3*dy[1] + S15*(y*dy[4] + zz*dy[7] + x*dy[8]);
  float duy = S3*dy[2] + S15*(x*dy[4] + zz*dy[5] - y*dy[8]);
  float duz = S3*dy[3] + S15*(y*dy[5] + x*dy[7]) + 3.0f*S5*zz*dy[6];
  float udot = x*dux + y*duy + zz*duz;
  float gx = dr*x + invr*(dux - x*udot);
  float gy = dr*y + invr*(duy - y*udot);
  float gz = dr*zz + invr*(duz - zz*udot);
  if (j==0){
    float* gp2 = gF + (size_t)e*3;
    gp2[0]=gx; gp2[1]=gy; gp2[2]=gz;
  }
}

// ---------------- node-major force gather: F[n] = sum_rcvRange g - sum_listS g ----------------
__global__ void k_fsum(const int* __restrict__ offR, const int* __restrict__ cntS,
                       const int* __restrict__ listS,
                       const float* __restrict__ gF, float* __restrict__ F){
  int t = threadIdx.x;
  int lane = t & 63, wid = t >> 6;
  int sub = lane >> 3, j = lane & 7;
  int n = blockIdx.x*32 + wid*8 + sub;
  float fx=0.f, fy=0.f, fz=0.f;
  int p0 = offR[n], p1 = offR[n+1];
  for (int p=p0+j; p<p1; p+=8){
    fx += gF[(size_t)p*3+0]; fy += gF[(size_t)p*3+1]; fz += gF[(size_t)p*3+2];
  }
  int dSn = min(cntS[n], CAP);
  for (int k=j;k<dSn;k+=8){
    int p = listS[n*CAP+k];
    fx -= gF[(size_t)p*3+0]; fy -= gF[(size_t)p*3+1]; fz -= gF[(size_t)p*3+2];
  }
  fx += __shfl_xor(fx,1,64); fy += __shfl_xor(fy,1,64); fz += __shfl_xor(fz,1,64);
  fx += __shfl_xor(fx,2,64); fy += __shfl_xor(fy,2,64); fz += __shfl_xor(fz,2,64);
  fx += __shfl_xor(fx,4,64); fy += __shfl_xor(fy,4,64); fz += __shfl_xor(fz,4,64);
  if (j==0){
    F[n*3+0]=fx; F[n*3+1]=fy; F[n*3+2]=fz;
  }
}

extern "C" void kernel_launch(void* const* d_in, const int* in_sizes, int n_in,
                              void* d_out, int out_size, void* d_ws, size_t ws_size,
                              hipStream_t stream){
  (void)in_sizes; (void)n_in;
  const float* pos    = (const float*)d_in[0];
  const float* attrs  = (const float*)d_in[1];
  const float* shifts = (const float*)d_in[2];
  const float* ae     = (const float*)d_in[3];
  const float* Wemb   = (const float*)d_in[4];
  const float* Wup    = (const float*)d_in[5];
  const float* W1     = (const float*)d_in[6];
  const float* W2     = (const float*)d_in[7];
  const float* Wout   = (const float*)d_in[8];
  const float* Wskip  = (const float*)d_in[9];
  const float* wread0 = (const float*)d_in[10];
  const float* Wr1    = (const float*)d_in[11];
  const float* wr2    = (const float*)d_in[12];
  const int*   ei     = (const int*)d_in[13];
  const int*   batch  = (const int*)d_in[14];
  float* out = (float*)d_out;

  const size_t NEED = 430000000;
  char* base;
  if (ws_size >= NEED){
    base = (char*)d_ws;
  } else {
    void* p = nullptr;
    hipGetSymbolAddress(&p, HIP_SYMBOL(g_fallback));
    base = (char*)p;
  }
  size_t off = 0;
  auto alloc = [&](size_t bytes)->char*{
    char* p = base + off;
    off += ((bytes + 255)/256)*256;
    return p;
  };
  u16*   Y    = (u16*)  alloc((size_t)E_*8*2);
  float* u3   = (float*)alloc((size_t)E_*3*4);
  float* irr  = (float*)alloc((size_t)E_*4);
  float* xi   = (float*)alloc((size_t)E_*4);
  u16*   s1b  = (u16*)  alloc((size_t)E_*64*2);
  float* gF   = (float*)alloc((size_t)E_*3*4);
  u16*   tab  = (u16*)  alloc((size_t)(TAB+1)*256*2);
  u16*   hu1  = (u16*)  alloc((size_t)N_*9*64*2);
  u16*   agg0 = (u16*)  alloc((size_t)N_*9*64*2);   // f16; reused as dhu1
  float* agg1 = (float*)alloc((size_t)N_*64*4);
  float* h2   = (float*)alloc((size_t)N_*64*4);
  float* ga1  = (float*)alloc((size_t)N_*64*4);
  u16*   ga0  = (u16*)  alloc((size_t)N_*9*64*2);
  float* WembUp = (float*)alloc(256*4);
  float* WA   = (float*)alloc(4096*4);
  float* sa   = (float*)alloc(256*4);
  float* va   = (float*)alloc(64*4);
  float* sv   = (float*)alloc(4*4);
  float* CC   = (float*)alloc(1024*4);
  int* cnts  = (int*)alloc((size_t)3*N_*4);     // cntR | cntS | cntR2
  int* offR  = (int*)alloc((size_t)(N_+1)*4);
  int* pe    = (int*)alloc((size_t)E_*4);
  int* pSnd  = (int*)alloc((size_t)E_*4);
  int* pRcv  = (int*)alloc((size_t)E_*4);
  int* listS = (int*)alloc((size_t)N_*CAP*4);
  int* cntR = cnts;  int* cntS = cnts + N_;  int* cntR2 = cnts + 2*N_;
  u16* dhu1 = agg0;
  float* F = out + G_ + G_*3;

  hipMemsetAsync(d_out, 0, (size_t)out_size*sizeof(float), stream);
  hipMemsetAsync(cnts, 0, (size_t)3*N_*sizeof(int), stream);

  // edge renumbering (rcv-sorted dense p-space)
  k_cnt     <<<E_/256, 256, 0, stream>>>(ei, cntR);
  k_scan    <<<1, 256, 0, stream>>>(cntR, offR);
  k_perm    <<<E_/256, 256, 0, stream>>>(ei, offR, cntR2, cntS, pe, pSnd, pRcv, listS);

  // forward
  k_rtab    <<<(TAB+1+31)/32, 256, 0, stream>>>(W1, W2, tab);
  k_fwd_edge<<<E_/256, 256, 0, stream>>>(pos, shifts, pe, pSnd, pRcv, Y, u3, irr, xi);
  k_pre     <<<1, 256, 0, stream>>>(Wout, Wup + 4096, Wskip, wread0, Wemb, Wup, Wr1, Wout + 4096, WA, sa, va, sv, WembUp, CC);
  k_agg0    <<<N_/4, 256, 0, stream>>>(offR, pSnd, attrs, WembUp, tab, xi, Y, agg0);
  k_mm64<false,true,true><<<N_*9/32, 256, 0, stream>>>(agg0, WA, hu1, N_*9, 9, attrs, sa, nullptr);
  k_read0   <<<N_/32, 256, 0, stream>>>(agg0, va, sv, attrs, ae, batch, out);
  k_s1      <<<N_/4, 256, 0, stream>>>(cntS, listS, hu1, Y, s1b);
  k_agg1    <<<N_/4, 256, 0, stream>>>(offR, tab, xi, s1b, agg1);
  k_mm64<false,false,false><<<N_/32, 256, 0, stream>>>(agg1, Wout + 4096, h2, N_, 1, attrs, Wskip + 256, nullptr);
  k_read1   <<<N_/16, 256, 0, stream>>>(h2, Wr1, wr2, batch, CC, ga1, out);

  // backward
  k_dhu1    <<<N_/4, 256, 0, stream>>>(cntS, listS, pRcv, tab, xi, ga1, Y, dhu1);
  k_mm64<true,true,true><<<N_*9/32, 256, 0, stream>>>(dhu1, WA, ga0, N_*9, 9, nullptr, nullptr, va);
  k_bedge_all<<<E_/16, 256, 0, stream>>>(pSnd, pRcv, Y, u3, irr, tab, xi, ga1, ga0, attrs, WembUp, hu1, gF);
  k_fsum    <<<N_/32, 256, 0, stream>>>(offR, cntS, listS, gF, F);
}